// Round 13
// baseline (390.274 us; speedup 1.0000x reference)
//
#include <hip/hip_runtime.h>
#include <hip/hip_bf16.h>
#include <hip/hip_cooperative_groups.h>
#include <math.h>

namespace cg = cooperative_groups;

#define NROWS 2048
#define BITS  64
#define NCLS  100
#define ALPHA_C  1.0f
#define LAMBDA_C 1.0f
#define ECLAMP   1.0e9f   // setup-clamp: Eb*ep <= 1e18, pair product <= 1e36 (finite)
#define NPMAX    64       // pos-list capacity (np ~ 20.5 +/- 4.5; 64 = +9.7 sigma)
#define EPS      20       // epT LDS row stride (floats): quads land on disjoint banks

typedef __bf16 bf16x8 __attribute__((ext_vector_type(8)));
typedef float  floatx4 __attribute__((ext_vector_type(4)));

// ---------------------------------------------------------------------------
// ws layout (same as round 12):
//   [0,      2048)   uchar lab8[2048]
//   [8192,  16384)   float rl[2048]
//   [16384, 24576)   int   npg[2048]
//   [24576, 24832)   float qp[64]
//   [32768, 557056)  float Ep[2048][64]
//   [557056,819200)  ushort ub[2048*64]
// Round 13: single cooperative launch (1024 blocks, exactly co-resident at
// 4 blocks/CU) runs prep -> posk -> eval -> finalize with grid.sync()
// between phases — removes 3 graph nodes + keeps L2 hot. Falls back to the
// validated round-12 4-node pipeline if the cooperative launch is rejected.
// Harness poison fill (~41 us) is a fixed floor.
// ---------------------------------------------------------------------------

__device__ __forceinline__ float block_reduce_sum(float v, float* wsum) {
    __syncthreads();
    #pragma unroll
    for (int off = 32; off > 0; off >>= 1) v += __shfl_down(v, off);
    int tid = threadIdx.x;
    if ((tid & 63) == 0) wsum[tid >> 6] = v;
    __syncthreads();
    float r = 0.f;
    if (tid == 0) {
        #pragma unroll
        for (int w = 0; w < 4; ++w) r += wsum[w];
    }
    return r;
}

__device__ __forceinline__ float softplus_mt(float T) {
    return fmaxf(-T, 0.f) + __logf(1.f + __expf(-fabsf(T)));
}

// ===========================================================================
// Phase bodies (device functions, shared by mega-kernel and fallback kernels)
// ===========================================================================

__device__ void phaseA_convert(const float* __restrict__ u, int blk,
                               unsigned short* __restrict__ ub,
                               float* __restrict__ qp, float* wsumA) {
    const int tid = threadIdx.x;
    const int base = blk * 2048 + tid * 8;
    float4 v0 = *(const float4*)(u + base);
    float4 v1 = *(const float4*)(u + base + 4);
    float vv[8] = {v0.x, v0.y, v0.z, v0.w, v1.x, v1.y, v1.z, v1.w};
    unsigned short ob[8];
    float q = 0.f;
    #pragma unroll
    for (int m = 0; m < 8; ++m) {
        const float v = vv[m];
        const float sg = (v > 0.f) ? 1.f : ((v < 0.f) ? -1.f : 0.f);
        const float d = v - sg;
        q = fmaf(d, d, q);
        __hip_bfloat16 h = __float2bfloat16(v);   // RNE
        ob[m] = *reinterpret_cast<unsigned short*>(&h);
    }
    *(uint4*)(ub + base) = *(const uint4*)ob;
    float t = block_reduce_sum(q, wsumA);
    if (tid == 0) qp[blk] = t;
}

__device__ void phaseA_labels(const float* __restrict__ y, int bi,
                              unsigned char* __restrict__ lab8,
                              float* __restrict__ rl) {
    const int tid = threadIdx.x;
    if (tid == 0) ((float4*)rl)[bi] = make_float4(0.f, 0.f, 0.f, 0.f);
    const int row = bi * 4 + (tid >> 6);
    const int lane = tid & 63;
    const float* yr = y + (size_t)row * NCLS;
    float v0 = yr[lane];
    float v1 = (lane < NCLS - 64) ? yr[lane + 64] : 0.f;
    unsigned long long m0 = __ballot(v0 > 0.5f);
    unsigned long long m1 = __ballot(v1 > 0.5f);
    if (lane == 0) {
        int c = m0 ? (__ffsll(m0) - 1) : (m1 ? 64 + __ffsll(m1) - 1 : 0);
        lab8[row] = (unsigned char)c;
    }
}

// one wave per row: ballot-compact matched j's (no dots under divergence),
// then one parallel dot pass (lane l < np). Ep rows zero-padded to 64.
__device__ void phaseB_pos(const float* __restrict__ u,
                           const unsigned char* __restrict__ lab8, int blk,
                           float* __restrict__ Ep, int* __restrict__ npg,
                           unsigned char* labL, float (*uloc)[BITS],
                           int (*lstJ)[NPMAX]) {
    const int tid = threadIdx.x;
    const int wave = tid >> 6;
    const int lane = tid & 63;
    const int row = blk * 4 + wave;

    ((uint2*)labL)[tid] = ((const uint2*)lab8)[tid];
    uloc[wave][lane] = u[(size_t)row * BITS + lane];
    __syncthreads();

    const int ci = labL[row];
    int np = 0;
    #pragma unroll 4
    for (int m = 0; m < NROWS / 64; ++m) {
        const int j = m * 64 + lane;
        const bool match = (labL[j] == ci);
        unsigned long long bal = __ballot(match);
        if (bal) {
            if (match) {
                const unsigned long long below = (lane == 0) ? 0ull : (bal << (64 - lane));
                const int slot = np + __popcll(below);
                if (slot < NPMAX) lstJ[wave][slot] = j;
            }
            np += __popcll(bal);
        }
    }
    const int npc = (np < NPMAX) ? np : NPMAX;

    float val = 0.f;
    if (lane < npc) {
        const int j = lstJ[wave][lane];
        const float4* uj4 = (const float4*)(u + (size_t)j * BITS);
        float s0 = 0.f, s1 = 0.f, s2 = 0.f, s3 = 0.f;
        #pragma unroll
        for (int kk = 0; kk < BITS / 4; ++kk) {
            float4 vj = uj4[kk];
            s0 = fmaf(vj.x, uloc[wave][4 * kk + 0], s0);
            s1 = fmaf(vj.y, uloc[wave][4 * kk + 1], s1);
            s2 = fmaf(vj.z, uloc[wave][4 * kk + 2], s2);
            s3 = fmaf(vj.w, uloc[wave][4 * kk + 3], s3);
        }
        val = fminf(__expf(-((s0 + s1) + (s2 + s3))), ECLAMP);
    }
    Ep[(size_t)row * NPMAX + lane] = val;
    if (lane == 0) npg[row] = np;
}

// register-resident MFMA + pair-product eval: 16 rows x 256 cols per block.
__device__ void phaseC_eval(const unsigned short* __restrict__ ub,
                            const unsigned char* __restrict__ lab8,
                            const float* __restrict__ Ep,
                            const int* __restrict__ npg, int blk,
                            float* __restrict__ rl,
                            unsigned char* labL, float (*epT)[EPS],
                            int* np16, float (*wsum16)[4]) {
    const int tid  = threadIdx.x;
    const int wave = tid >> 6;
    const int lane = tid & 63;
    const int rsel = lane & 15;
    const int quad = lane >> 4;
    const int koff = quad * 8;
    const int i0    = (blk >> 3) * 16;
    const int jbase = (blk & 7) * 256;

    ((uint2*)labL)[tid] = ((const uint2*)lab8)[tid];
    #pragma unroll
    for (int it = 0; it < 4; ++it) {
        const int idx = tid + it * 256;
        const int r = idx >> 6, k = idx & 63;
        epT[k][r] = Ep[(size_t)(i0 + r) * NPMAX + k];
    }
    if (tid < 16) np16[tid] = npg[i0 + tid];

    uint4 a0r = *(const uint4*)(ub + (size_t)(i0 + rsel) * BITS + koff);
    uint4 a1r = *(const uint4*)(ub + (size_t)(i0 + rsel) * BITS + 32 + koff);
    bf16x8 A0 = __builtin_bit_cast(bf16x8, a0r);
    bf16x8 A1 = __builtin_bit_cast(bf16x8, a1r);

    float Eb[4][4];
    #pragma unroll
    for (int t = 0; t < 4; ++t) {
        const int jr = jbase + (wave * 4 + t) * 16 + rsel;
        uint4 b0r = *(const uint4*)(ub + (size_t)jr * BITS + koff);
        uint4 b1r = *(const uint4*)(ub + (size_t)jr * BITS + 32 + koff);
        bf16x8 B0 = __builtin_bit_cast(bf16x8, b0r);
        bf16x8 B1 = __builtin_bit_cast(bf16x8, b1r);
        floatx4 c = {0.f, 0.f, 0.f, 0.f};
        c = __builtin_amdgcn_mfma_f32_16x16x32_bf16(A0, B0, c, 0, 0, 0);
        c = __builtin_amdgcn_mfma_f32_16x16x32_bf16(A1, B1, c, 0, 0, 0);
        #pragma unroll
        for (int r = 0; r < 4; ++r) {
            const int rowLab = labL[i0 + 4 * quad + r];
            const int colLab = labL[jr];
            Eb[t][r] = (colLab == rowLab) ? 0.f
                                          : fminf(__expf(c[r] + ALPHA_C), ECLAMP);
        }
    }
    __syncthreads();

    int npmx = 0;
    #pragma unroll
    for (int r = 0; r < 16; ++r) {
        int n = np16[r]; n = (n > NPMAX) ? NPMAX : n;
        npmx = (n > npmx) ? n : npmx;
    }
    const int npr = (npmx + 1) & ~1;

    float s[4] = {0.f, 0.f, 0.f, 0.f};
    for (int k = 0; k < npr; k += 2) {
        const float4 e0 = *(const float4*)(&epT[k][4 * quad]);
        const float4 e1 = *(const float4*)(&epT[k + 1][4 * quad]);
        const float e0v[4] = {e0.x, e0.y, e0.z, e0.w};
        const float e1v[4] = {e1.x, e1.y, e1.z, e1.w};
        #pragma unroll
        for (int t = 0; t < 4; ++t) {
            #pragma unroll
            for (int r = 0; r < 4; ++r) {
                const float q0 = Eb[t][r];
                const float f = fmaf(q0, e0v[r], 1.f);
                const float g = fmaf(q0, e1v[r], 1.f);
                s[r] += __log2f(f * g);
            }
        }
    }

    #pragma unroll
    for (int r = 0; r < 4; ++r) {
        #pragma unroll
        for (int off = 1; off < 16; off <<= 1) s[r] += __shfl_xor(s[r], off);
    }
    if (rsel == 0) {
        #pragma unroll
        for (int r = 0; r < 4; ++r) wsum16[4 * quad + r][wave] = s[r];
    }
    __syncthreads();
    if (tid < 16) {
        const float ln2 = 0.6931471805599453f;
        const float tot = ((wsum16[tid][0] + wsum16[tid][1]) +
                           (wsum16[tid][2] + wsum16[tid][3])) * ln2;
        atomicAdd(&rl[i0 + tid], tot);
    }
}

__device__ void phaseD_final(const float* __restrict__ rl,
                             const int* __restrict__ npg,
                             const float* __restrict__ qp,
                             float* __restrict__ out, float* wsumA) {
    const int tid = threadIdx.x;
    float t = 0.f, v = 0.f;
    for (int row = tid; row < NROWS; row += 256) {
        const int np = npg[row];
        const int nneg = NROWS - np;
        const int valid = (np > 0 && nneg > 0) ? 1 : 0;
        t += valid ? (rl[row] / fmaxf((float)np * (float)nneg, 1.f)) : 0.f;
        v += (float)valid;
    }
    float q = (tid < 64) ? qp[tid] : 0.f;
    float tt = block_reduce_sum(t, wsumA);
    float vv = block_reduce_sum(v, wsumA);
    float qq = block_reduce_sum(q, wsumA);
    if (tid == 0) {
        const float loss1 = (vv > 0.f) ? (tt / fmaxf(vv, 1.f)) : 0.f;
        const float loss2 = LAMBDA_C * (qq / (float)(NROWS * BITS));
        out[0] = loss1 + loss2;
    }
}

// ===========================================================================
// Cooperative mega-kernel: all phases in one launch.
// ===========================================================================
__global__ __launch_bounds__(256, 4) void mega_kernel(const float* __restrict__ u,
                                                      const float* __restrict__ y,
                                                      unsigned short* __restrict__ ub,
                                                      unsigned char* __restrict__ lab8,
                                                      float* __restrict__ qp,
                                                      float* __restrict__ rl,
                                                      float* __restrict__ Ep,
                                                      int* __restrict__ npg,
                                                      float* __restrict__ out) {
    __shared__ unsigned char labL[NROWS];         // 2 KB
    __shared__ float uloc[4][BITS];               // 1 KB
    __shared__ int   lstJ[4][NPMAX];              // 1 KB
    alignas(16) __shared__ float epT[NPMAX][EPS]; // 5 KB
    __shared__ int np16[16];
    __shared__ float wsum16[16][4];
    __shared__ float wsumA[4];

    cg::grid_group grid = cg::this_grid();
    const int b = blockIdx.x;

    // Phase A: convert+quant (blocks 0-63), labels + rl-zero (blocks 512-1023)
    if (b < 64)        phaseA_convert(u, b, ub, qp, wsumA);
    else if (b >= 512) phaseA_labels(y, b - 512, lab8, rl);
    grid.sync();

    // Phase B: global pos-exp lists (blocks 0-511, one wave per row)
    if (b < 512) phaseB_pos(u, lab8, b, Ep, npg, labL, uloc, lstJ);
    grid.sync();

    // Phase C: register-resident MFMA + eval (all 1024 blocks)
    phaseC_eval(ub, lab8, Ep, npg, b, rl, labL, epT, np16, wsum16);
    grid.sync();

    // Phase D: finalize (block 0)
    if (b == 0) phaseD_final(rl, npg, qp, out, wsumA);
}

// ===========================================================================
// Round-12 4-node pipeline (fallback if cooperative launch is rejected)
// ===========================================================================

__global__ __launch_bounds__(256) void prep_kernel(const float* __restrict__ u,
                                                   const float* __restrict__ y,
                                                   unsigned short* __restrict__ ub,
                                                   unsigned char* __restrict__ lab8,
                                                   float* __restrict__ qp,
                                                   float* __restrict__ rl) {
    __shared__ float wsumA[4];
    if (blockIdx.x < 64) phaseA_convert(u, blockIdx.x, ub, qp, wsumA);
    else                 phaseA_labels(y, blockIdx.x - 64, lab8, rl);
}

__global__ __launch_bounds__(256) void posk_kernel(const float* __restrict__ u,
                                                   const unsigned char* __restrict__ lab8,
                                                   float* __restrict__ Ep,
                                                   int* __restrict__ npg) {
    __shared__ unsigned char labL[NROWS];
    __shared__ float uloc[4][BITS];
    __shared__ int   lstJ[4][NPMAX];
    phaseB_pos(u, lab8, blockIdx.x, Ep, npg, labL, uloc, lstJ);
}

__global__ __launch_bounds__(256, 4) void evalj2_kernel(const unsigned short* __restrict__ ub,
                                                        const unsigned char* __restrict__ lab8,
                                                        const float* __restrict__ Ep,
                                                        const int* __restrict__ npg,
                                                        float* __restrict__ rl) {
    __shared__ unsigned char labL[NROWS];
    alignas(16) __shared__ float epT[NPMAX][EPS];
    __shared__ int np16[16];
    __shared__ float wsum16[16][4];
    phaseC_eval(ub, lab8, Ep, npg, blockIdx.x, rl, labL, epT, np16, wsum16);
}

__global__ __launch_bounds__(256) void finalize3_kernel(const float* __restrict__ rl,
                                                        const int* __restrict__ npg,
                                                        const float* __restrict__ qp,
                                                        float* __restrict__ out) {
    __shared__ float wsumA[4];
    phaseD_final(rl, npg, qp, out, wsumA);
}

// ===========================================================================
// Fallback path (small ws) — unchanged (passed round 1)
// ===========================================================================

__global__ __launch_bounds__(256) void labels_only_kernel(const float* __restrict__ y,
                                                          int* __restrict__ labels) {
    const int tid = threadIdx.x;
    const int row = blockIdx.x * 4 + (tid >> 6);
    const int lane = tid & 63;
    const float* yr = y + (size_t)row * NCLS;
    float v0 = yr[lane];
    float v1 = (lane < NCLS - 64) ? yr[lane + 64] : 0.f;
    unsigned long long m0 = __ballot(v0 > 0.5f);
    unsigned long long m1 = __ballot(v1 > 0.5f);
    if (lane == 0) {
        int c = m0 ? (__ffsll(m0) - 1) : (m1 ? 64 + __ffsll(m1) - 1 : 0);
        labels[row] = c;
    }
}

__global__ __launch_bounds__(256) void row_loss_kernel(const float* __restrict__ u,
                                                       const int* __restrict__ labels,
                                                       float* __restrict__ acc) {
    __shared__ float a[NROWS];
    __shared__ float apv[NROWS];
    __shared__ int lab[NROWS];
    __shared__ float ui[BITS];
    __shared__ int npos_s;
    __shared__ float wsum[4];

    const int i = blockIdx.x;
    const int tid = threadIdx.x;

    if (tid < BITS) ui[tid] = u[(size_t)i * BITS + tid];
    if (tid == 0) npos_s = 0;
    __syncthreads();

    #pragma unroll
    for (int m = 0; m < NROWS / 256; ++m) {
        const int j = tid + m * 256;
        const float4* uj = (const float4*)(u + (size_t)j * BITS);
        float s0 = 0.f, s1 = 0.f, s2 = 0.f, s3 = 0.f;
        #pragma unroll
        for (int q = 0; q < BITS / 4; ++q) {
            float4 v = uj[q];
            s0 = fmaf(v.x, ui[4 * q + 0], s0);
            s1 = fmaf(v.y, ui[4 * q + 1], s1);
            s2 = fmaf(v.z, ui[4 * q + 2], s2);
            s3 = fmaf(v.w, ui[4 * q + 3], s3);
        }
        a[j] = (s0 + s1) + (s2 + s3);
        lab[j] = labels[j];
    }
    __syncthreads();

    const int c = lab[i];
    #pragma unroll
    for (int m = 0; m < NROWS / 256; ++m) {
        const int j = tid + m * 256;
        if (lab[j] == c) { int k = atomicAdd(&npos_s, 1); apv[k] = a[j]; }
    }
    __syncthreads();
    const int npos = npos_s;
    const int nneg = NROWS - npos;

    float bb[NROWS / 256];
    #pragma unroll
    for (int m = 0; m < NROWS / 256; ++m) {
        const int j = tid + m * 256;
        bb[m] = (lab[j] != c) ? (a[j] + ALPHA_C) : -3.0e38f;
    }

    float lsum = 0.f;
    for (int k = 0; k < npos; ++k) {
        const float apk = apv[k];
        #pragma unroll
        for (int m = 0; m < NROWS / 256; ++m) lsum += softplus_mt(apk - bb[m]);
    }

    float tot = block_reduce_sum(lsum, wsum);
    if (tid == 0) {
        const int valid = (npos > 0 && nneg > 0) ? 1 : 0;
        const float npairs = fmaxf((float)npos * (float)nneg, 1.f);
        const float rlv = valid ? (tot / npairs) : 0.f;
        atomicAdd(&acc[0], rlv);
        atomicAdd(&acc[1], (float)valid);
    }
}

__global__ __launch_bounds__(256) void quant_kernel(const float* __restrict__ u,
                                                    float* __restrict__ acc) {
    __shared__ float wsum[4];
    const int stride = gridDim.x * 256;
    float s = 0.f;
    for (int t = blockIdx.x * 256 + threadIdx.x; t < NROWS * BITS; t += stride) {
        float v = u[t];
        float sg = (v > 0.f) ? 1.f : ((v < 0.f) ? -1.f : 0.f);
        float d = v - sg;
        s = fmaf(d, d, s);
    }
    float tot = block_reduce_sum(s, wsum);
    if (threadIdx.x == 0) atomicAdd(&acc[2], tot);
}

__global__ void finalize_kernel(const float* __restrict__ acc,
                                float* __restrict__ out) {
    const float tot = acc[0], cnt = acc[1], q = acc[2];
    const float loss1 = (cnt > 0.f) ? (tot / fmaxf(cnt, 1.f)) : 0.f;
    const float loss2 = LAMBDA_C * (q / (float)(NROWS * BITS));
    out[0] = loss1 + loss2;
}

// ===========================================================================

extern "C" void kernel_launch(void* const* d_in, const int* in_sizes, int n_in,
                              void* d_out, int out_size, void* d_ws, size_t ws_size,
                              hipStream_t stream) {
    const float* u = (const float*)d_in[0];   // [2048, 64]
    const float* y = (const float*)d_in[1];   // [2048, 100]
    float* out = (float*)d_out;

    unsigned char* lab8 = (unsigned char*)d_ws;
    float* rl  = (float*)((char*)d_ws + 8192);
    int*   npg = (int*)((char*)d_ws + 16384);
    float* qp  = (float*)((char*)d_ws + 24576);
    float* Ep  = (float*)((char*)d_ws + 32768);
    unsigned short* ub = (unsigned short*)((char*)d_ws + 557056);
    const size_t NEED = 557056 + (size_t)NROWS * BITS * sizeof(unsigned short);

    if (ws_size >= NEED) {
        const float* ua = u; const float* ya = y;
        unsigned short* uba = ub; unsigned char* la = lab8;
        float* qpa = qp; float* rla = rl; float* Epa = Ep;
        int* npga = npg; float* outa = out;
        void* args[] = {&ua, &ya, &uba, &la, &qpa, &rla, &Epa, &npga, &outa};
        hipError_t err = hipLaunchCooperativeKernel((const void*)mega_kernel,
                                                    dim3(1024), dim3(256),
                                                    args, 0, stream);
        if (err != hipSuccess) {
            (void)hipGetLastError();   // clear, fall back to 4-node pipeline
            prep_kernel<<<576, 256, 0, stream>>>(u, y, ub, lab8, qp, rl);
            posk_kernel<<<512, 256, 0, stream>>>(u, lab8, Ep, npg);
            evalj2_kernel<<<1024, 256, 0, stream>>>(ub, lab8, Ep, npg, rl);
            finalize3_kernel<<<1, 256, 0, stream>>>(rl, npg, qp, out);
        }
    } else {
        float* acc2 = (float*)d_ws;
        int*   lab2 = (int*)((char*)d_ws + 256);
        hipMemsetAsync(d_ws, 0, 256, stream);
        labels_only_kernel<<<512, 256, 0, stream>>>(y, lab2);
        row_loss_kernel<<<NROWS, 256, 0, stream>>>(u, lab2, acc2);
        quant_kernel<<<64, 256, 0, stream>>>(u, acc2);
        finalize_kernel<<<1, 1, 0, stream>>>(acc2, out);
    }
}

// Round 14
// 91.293 us; speedup vs baseline: 4.2750x; 4.2750x over previous
//
#include <hip/hip_runtime.h>
#include <hip/hip_bf16.h>
#include <math.h>

#define NROWS 2048
#define BITS  64
#define NCLS  100
#define ALPHA_C  1.0f
#define LAMBDA_C 1.0f
#define ECLAMP   1.0e9f   // setup-clamp: Eb*ep <= 1e18, pair product <= 1e36 (finite)
#define NPMAX    64       // pos-list capacity (np ~ 20.5 +/- 4.5; 64 = +9.7 sigma)
#define EPS      20       // epT LDS row stride (floats): 80B keeps b128 reads 16B-aligned

typedef __bf16 bf16x8 __attribute__((ext_vector_type(8)));
typedef float  floatx4 __attribute__((ext_vector_type(4)));

// ---------------------------------------------------------------------------
// ws layout:
//   [0,      2048)   uchar lab8[2048]
//   [8192,  16384)   float rl[2048]     (prep zeroes)
//   [16384, 24576)   int   npg[2048]
//   [24576, 24832)   float qp[64]
//   [24832, 24836)   uint  counter      (prep zeroes; eval last-block finalize)
//   [32768, 557056)  float Ep[2048][64]
//   [557056,819200)  ushort ub[2048*64]
// 3-node pipeline: prep -> posk -> evalj3 (finalize folded in via completion
// counter). Round-13 lesson: grid.sync() costs ~100 us/sync on this stack —
// separate kernel nodes ARE the cheap inter-phase barrier. Harness ws poison
// fill (~41 us @ >80% HBM peak) is a fixed floor under everything.
// ---------------------------------------------------------------------------

__device__ __forceinline__ float block_reduce_sum(float v, float* wsum) {
    __syncthreads();
    #pragma unroll
    for (int off = 32; off > 0; off >>= 1) v += __shfl_down(v, off);
    int tid = threadIdx.x;
    if ((tid & 63) == 0) wsum[tid >> 6] = v;
    __syncthreads();
    float r = 0.f;
    if (tid == 0) {
        #pragma unroll
        for (int w = 0; w < 4; ++w) r += wsum[w];
    }
    return r;
}

__device__ __forceinline__ float softplus_mt(float T) {
    return fmaxf(-T, 0.f) + __logf(1.f + __expf(-fabsf(T)));
}

// ===========================================================================
// Fast path
// ===========================================================================

// blocks [0,64): u -> bf16 (RNE) + quant partials.
// blocks [64,576): labels via ballot + zero rl; block 64 zeroes the counter.
__global__ __launch_bounds__(256) void prep_kernel(const float* __restrict__ u,
                                                   const float* __restrict__ y,
                                                   unsigned short* __restrict__ ub,
                                                   unsigned char* __restrict__ lab8,
                                                   float* __restrict__ qp,
                                                   float* __restrict__ rl,
                                                   unsigned int* __restrict__ counter) {
    const int tid = threadIdx.x;
    if (blockIdx.x < 64) {
        __shared__ float wsum[4];
        const int base = blockIdx.x * 2048 + tid * 8;
        float4 v0 = *(const float4*)(u + base);
        float4 v1 = *(const float4*)(u + base + 4);
        float vv[8] = {v0.x, v0.y, v0.z, v0.w, v1.x, v1.y, v1.z, v1.w};
        unsigned short ob[8];
        float q = 0.f;
        #pragma unroll
        for (int m = 0; m < 8; ++m) {
            const float v = vv[m];
            const float sg = (v > 0.f) ? 1.f : ((v < 0.f) ? -1.f : 0.f);
            const float d = v - sg;
            q = fmaf(d, d, q);
            __hip_bfloat16 h = __float2bfloat16(v);   // RNE
            ob[m] = *reinterpret_cast<unsigned short*>(&h);
        }
        *(uint4*)(ub + base) = *(const uint4*)ob;
        float t = block_reduce_sum(q, wsum);
        if (tid == 0) qp[blockIdx.x] = t;
    } else {
        const int bi = blockIdx.x - 64;               // 0..511
        if (tid == 0) {
            ((float4*)rl)[bi] = make_float4(0.f, 0.f, 0.f, 0.f);
            if (bi == 0) *counter = 0u;
        }
        const int row = bi * 4 + (tid >> 6);
        const int lane = tid & 63;
        const float* yr = y + (size_t)row * NCLS;
        float v0 = yr[lane];
        float v1 = (lane < NCLS - 64) ? yr[lane + 64] : 0.f;
        unsigned long long m0 = __ballot(v0 > 0.5f);
        unsigned long long m1 = __ballot(v1 > 0.5f);
        if (lane == 0) {
            int c = m0 ? (__ffsll(m0) - 1) : (m1 ? 64 + __ffsll(m1) - 1 : 0);
            lab8[row] = (unsigned char)c;
        }
    }
}

// Global pos-exp lists, computed ONCE. One wave per row (512 blocks x 4 waves).
// Phase A: ballot-scan labels, compact matched j's (no dots under divergence).
// Phase B: one parallel dot pass (lane l < np). Ep rows zero-padded to 64.
__global__ __launch_bounds__(256) void posk_kernel(const float* __restrict__ u,
                                                   const unsigned char* __restrict__ lab8,
                                                   float* __restrict__ Ep,
                                                   int* __restrict__ npg) {
    __shared__ unsigned char labL[NROWS];   // 2 KB
    __shared__ float uloc[4][BITS];         // 1 KB
    __shared__ int   lstJ[4][NPMAX];        // 1 KB
    const int tid = threadIdx.x;
    const int wave = tid >> 6;
    const int lane = tid & 63;
    const int row = blockIdx.x * 4 + wave;

    ((uint2*)labL)[tid] = ((const uint2*)lab8)[tid];
    uloc[wave][lane] = u[(size_t)row * BITS + lane];
    __syncthreads();

    const int ci = labL[row];
    int np = 0;
    #pragma unroll 4
    for (int m = 0; m < NROWS / 64; ++m) {
        const int j = m * 64 + lane;
        const bool match = (labL[j] == ci);
        unsigned long long bal = __ballot(match);
        if (bal) {
            if (match) {
                const unsigned long long below = (lane == 0) ? 0ull : (bal << (64 - lane));
                const int slot = np + __popcll(below);
                if (slot < NPMAX) lstJ[wave][slot] = j;
            }
            np += __popcll(bal);
        }
    }
    const int npc = (np < NPMAX) ? np : NPMAX;

    float val = 0.f;   // zero-pad default
    if (lane < npc) {
        const int j = lstJ[wave][lane];
        const float4* uj4 = (const float4*)(u + (size_t)j * BITS);
        float s0 = 0.f, s1 = 0.f, s2 = 0.f, s3 = 0.f;
        #pragma unroll
        for (int kk = 0; kk < BITS / 4; ++kk) {
            float4 vj = uj4[kk];
            s0 = fmaf(vj.x, uloc[wave][4 * kk + 0], s0);
            s1 = fmaf(vj.y, uloc[wave][4 * kk + 1], s1);
            s2 = fmaf(vj.z, uloc[wave][4 * kk + 2], s2);
            s3 = fmaf(vj.w, uloc[wave][4 * kk + 3], s3);
        }
        val = fminf(__expf(-((s0 + s1) + (s2 + s3))), ECLAMP);
    }
    Ep[(size_t)row * NPMAX + lane] = val;
    if (lane == 0) npg[row] = np;
}

// Register-resident MFMA + eval (R12-validated core) + last-block finalize.
// Grid 1024 = 128 i-tiles x 8 j-eighths; block = 16 rows x 256 cols; all 4
// C-regs used. Pos lists via transposed LDS tile (conflict-free b128 reads).
// Pair-product log2 (setup clamp 1e9; caps terms at 41.4, ~2e-4 of pairs,
// loss error ~6e-4 << 0.104 threshold). Last finishing block reduces rl/npg/qp
// into out — one fewer graph node than R12.
__global__ __launch_bounds__(256, 6) void evalj3_kernel(const unsigned short* __restrict__ ub,
                                                        const unsigned char* __restrict__ lab8,
                                                        const float* __restrict__ Ep,
                                                        const int* __restrict__ npg,
                                                        const float* __restrict__ qp,
                                                        float* __restrict__ rl,
                                                        unsigned int* __restrict__ counter,
                                                        float* __restrict__ out) {
    __shared__ unsigned char labL[NROWS];     // 2 KB
    alignas(16) __shared__ float epT[NPMAX][EPS];  // 5 KB
    __shared__ int np16[16];
    __shared__ float wsum16[16][4];
    __shared__ float wsumA[4];
    __shared__ int lastFlag;

    const int tid  = threadIdx.x;
    const int wave = tid >> 6;
    const int lane = tid & 63;
    const int rsel = lane & 15;
    const int quad = lane >> 4;
    const int koff = quad * 8;
    const int i0    = (blockIdx.x >> 3) * 16;
    const int jbase = (blockIdx.x & 7) * 256;

    ((uint2*)labL)[tid] = ((const uint2*)lab8)[tid];
    #pragma unroll
    for (int it = 0; it < 4; ++it) {
        const int idx = tid + it * 256;
        const int r = idx >> 6, k = idx & 63;
        epT[k][r] = Ep[(size_t)(i0 + r) * NPMAX + k];
    }
    if (tid < 16) np16[tid] = npg[i0 + tid];

    uint4 a0r = *(const uint4*)(ub + (size_t)(i0 + rsel) * BITS + koff);
    uint4 a1r = *(const uint4*)(ub + (size_t)(i0 + rsel) * BITS + 32 + koff);
    bf16x8 A0 = __builtin_bit_cast(bf16x8, a0r);
    bf16x8 A1 = __builtin_bit_cast(bf16x8, a1r);

    float Eb[4][4];
    #pragma unroll
    for (int t = 0; t < 4; ++t) {
        const int jr = jbase + (wave * 4 + t) * 16 + rsel;
        uint4 b0r = *(const uint4*)(ub + (size_t)jr * BITS + koff);
        uint4 b1r = *(const uint4*)(ub + (size_t)jr * BITS + 32 + koff);
        bf16x8 B0 = __builtin_bit_cast(bf16x8, b0r);
        bf16x8 B1 = __builtin_bit_cast(bf16x8, b1r);
        floatx4 c = {0.f, 0.f, 0.f, 0.f};
        c = __builtin_amdgcn_mfma_f32_16x16x32_bf16(A0, B0, c, 0, 0, 0);
        c = __builtin_amdgcn_mfma_f32_16x16x32_bf16(A1, B1, c, 0, 0, 0);
        #pragma unroll
        for (int r = 0; r < 4; ++r) {
            const int rowLab = labL[i0 + 4 * quad + r];
            const int colLab = labL[jr];
            Eb[t][r] = (colLab == rowLab) ? 0.f
                                          : fminf(__expf(c[r] + ALPHA_C), ECLAMP);
        }
    }
    __syncthreads();

    int npmx = 0;
    #pragma unroll
    for (int r = 0; r < 16; ++r) {
        int n = np16[r]; n = (n > NPMAX) ? NPMAX : n;
        npmx = (n > npmx) ? n : npmx;
    }
    const int npr = (npmx + 1) & ~1;

    float s[4] = {0.f, 0.f, 0.f, 0.f};
    for (int k = 0; k < npr; k += 2) {
        const float4 e0 = *(const float4*)(&epT[k][4 * quad]);
        const float4 e1 = *(const float4*)(&epT[k + 1][4 * quad]);
        const float e0v[4] = {e0.x, e0.y, e0.z, e0.w};
        const float e1v[4] = {e1.x, e1.y, e1.z, e1.w};
        #pragma unroll
        for (int t = 0; t < 4; ++t) {
            #pragma unroll
            for (int r = 0; r < 4; ++r) {
                const float q0 = Eb[t][r];
                const float f = fmaf(q0, e0v[r], 1.f);
                const float g = fmaf(q0, e1v[r], 1.f);
                s[r] += __log2f(f * g);
            }
        }
    }

    #pragma unroll
    for (int r = 0; r < 4; ++r) {
        #pragma unroll
        for (int off = 1; off < 16; off <<= 1) s[r] += __shfl_xor(s[r], off);
    }
    if (rsel == 0) {
        #pragma unroll
        for (int r = 0; r < 4; ++r) wsum16[4 * quad + r][wave] = s[r];
    }
    __syncthreads();
    if (tid < 16) {
        const float ln2 = 0.6931471805599453f;
        const float tot = ((wsum16[tid][0] + wsum16[tid][1]) +
                           (wsum16[tid][2] + wsum16[tid][3])) * ln2;
        atomicAdd(&rl[i0 + tid], tot);
    }
    if (tid == 0) {
        __threadfence();                      // rl adds visible before counting
        unsigned int old = atomicAdd(counter, 1u);
        lastFlag = (old == (unsigned int)(gridDim.x - 1)) ? 1 : 0;
    }
    __syncthreads();
    if (lastFlag) {
        float t = 0.f, v = 0.f;
        for (int row = tid; row < NROWS; row += 256) {
            const int np = npg[row];              // prior kernel: plain load OK
            const int nneg = NROWS - np;
            const int valid = (np > 0 && nneg > 0) ? 1 : 0;
            const float rv = atomicAdd(&rl[row], 0.f);   // coherent read
            t += valid ? (rv / fmaxf((float)np * (float)nneg, 1.f)) : 0.f;
            v += (float)valid;
        }
        float q = (tid < 64) ? qp[tid] : 0.f;
        float tt = block_reduce_sum(t, wsumA);
        float vv = block_reduce_sum(v, wsumA);
        float qq = block_reduce_sum(q, wsumA);
        if (tid == 0) {
            const float loss1 = (vv > 0.f) ? (tt / fmaxf(vv, 1.f)) : 0.f;
            const float loss2 = LAMBDA_C * (qq / (float)(NROWS * BITS));
            out[0] = loss1 + loss2;
        }
    }
}

// ===========================================================================
// Fallback path (small ws) — unchanged (passed round 1)
// ===========================================================================

__global__ __launch_bounds__(256) void labels_only_kernel(const float* __restrict__ y,
                                                          int* __restrict__ labels) {
    const int tid = threadIdx.x;
    const int row = blockIdx.x * 4 + (tid >> 6);
    const int lane = tid & 63;
    const float* yr = y + (size_t)row * NCLS;
    float v0 = yr[lane];
    float v1 = (lane < NCLS - 64) ? yr[lane + 64] : 0.f;
    unsigned long long m0 = __ballot(v0 > 0.5f);
    unsigned long long m1 = __ballot(v1 > 0.5f);
    if (lane == 0) {
        int c = m0 ? (__ffsll(m0) - 1) : (m1 ? 64 + __ffsll(m1) - 1 : 0);
        labels[row] = c;
    }
}

__global__ __launch_bounds__(256) void row_loss_kernel(const float* __restrict__ u,
                                                       const int* __restrict__ labels,
                                                       float* __restrict__ acc) {
    __shared__ float a[NROWS];
    __shared__ float apv[NROWS];
    __shared__ int lab[NROWS];
    __shared__ float ui[BITS];
    __shared__ int npos_s;
    __shared__ float wsum[4];

    const int i = blockIdx.x;
    const int tid = threadIdx.x;

    if (tid < BITS) ui[tid] = u[(size_t)i * BITS + tid];
    if (tid == 0) npos_s = 0;
    __syncthreads();

    #pragma unroll
    for (int m = 0; m < NROWS / 256; ++m) {
        const int j = tid + m * 256;
        const float4* uj = (const float4*)(u + (size_t)j * BITS);
        float s0 = 0.f, s1 = 0.f, s2 = 0.f, s3 = 0.f;
        #pragma unroll
        for (int q = 0; q < BITS / 4; ++q) {
            float4 v = uj[q];
            s0 = fmaf(v.x, ui[4 * q + 0], s0);
            s1 = fmaf(v.y, ui[4 * q + 1], s1);
            s2 = fmaf(v.z, ui[4 * q + 2], s2);
            s3 = fmaf(v.w, ui[4 * q + 3], s3);
        }
        a[j] = (s0 + s1) + (s2 + s3);
        lab[j] = labels[j];
    }
    __syncthreads();

    const int c = lab[i];
    #pragma unroll
    for (int m = 0; m < NROWS / 256; ++m) {
        const int j = tid + m * 256;
        if (lab[j] == c) { int k = atomicAdd(&npos_s, 1); apv[k] = a[j]; }
    }
    __syncthreads();
    const int npos = npos_s;
    const int nneg = NROWS - npos;

    float bb[NROWS / 256];
    #pragma unroll
    for (int m = 0; m < NROWS / 256; ++m) {
        const int j = tid + m * 256;
        bb[m] = (lab[j] != c) ? (a[j] + ALPHA_C) : -3.0e38f;
    }

    float lsum = 0.f;
    for (int k = 0; k < npos; ++k) {
        const float apk = apv[k];
        #pragma unroll
        for (int m = 0; m < NROWS / 256; ++m) lsum += softplus_mt(apk - bb[m]);
    }

    float tot = block_reduce_sum(lsum, wsum);
    if (tid == 0) {
        const int valid = (npos > 0 && nneg > 0) ? 1 : 0;
        const float npairs = fmaxf((float)npos * (float)nneg, 1.f);
        const float rlv = valid ? (tot / npairs) : 0.f;
        atomicAdd(&acc[0], rlv);
        atomicAdd(&acc[1], (float)valid);
    }
}

__global__ __launch_bounds__(256) void quant_kernel(const float* __restrict__ u,
                                                    float* __restrict__ acc) {
    __shared__ float wsum[4];
    const int stride = gridDim.x * 256;
    float s = 0.f;
    for (int t = blockIdx.x * 256 + threadIdx.x; t < NROWS * BITS; t += stride) {
        float v = u[t];
        float sg = (v > 0.f) ? 1.f : ((v < 0.f) ? -1.f : 0.f);
        float d = v - sg;
        s = fmaf(d, d, s);
    }
    float tot = block_reduce_sum(s, wsum);
    if (threadIdx.x == 0) atomicAdd(&acc[2], tot);
}

__global__ void finalize_kernel(const float* __restrict__ acc,
                                float* __restrict__ out) {
    const float tot = acc[0], cnt = acc[1], q = acc[2];
    const float loss1 = (cnt > 0.f) ? (tot / fmaxf(cnt, 1.f)) : 0.f;
    const float loss2 = LAMBDA_C * (q / (float)(NROWS * BITS));
    out[0] = loss1 + loss2;
}

// ===========================================================================

extern "C" void kernel_launch(void* const* d_in, const int* in_sizes, int n_in,
                              void* d_out, int out_size, void* d_ws, size_t ws_size,
                              hipStream_t stream) {
    const float* u = (const float*)d_in[0];   // [2048, 64]
    const float* y = (const float*)d_in[1];   // [2048, 100]
    float* out = (float*)d_out;

    unsigned char* lab8 = (unsigned char*)d_ws;
    float* rl  = (float*)((char*)d_ws + 8192);
    int*   npg = (int*)((char*)d_ws + 16384);
    float* qp  = (float*)((char*)d_ws + 24576);
    unsigned int* counter = (unsigned int*)((char*)d_ws + 24832);
    float* Ep  = (float*)((char*)d_ws + 32768);
    unsigned short* ub = (unsigned short*)((char*)d_ws + 557056);
    const size_t NEED = 557056 + (size_t)NROWS * BITS * sizeof(unsigned short);

    if (ws_size >= NEED) {
        prep_kernel<<<576, 256, 0, stream>>>(u, y, ub, lab8, qp, rl, counter);
        posk_kernel<<<512, 256, 0, stream>>>(u, lab8, Ep, npg);
        evalj3_kernel<<<1024, 256, 0, stream>>>(ub, lab8, Ep, npg, qp, rl, counter, out);
    } else {
        float* acc2 = (float*)d_ws;
        int*   lab2 = (int*)((char*)d_ws + 256);
        hipMemsetAsync(d_ws, 0, 256, stream);
        labels_only_kernel<<<512, 256, 0, stream>>>(y, lab2);
        row_loss_kernel<<<NROWS, 256, 0, stream>>>(u, lab2, acc2);
        quant_kernel<<<64, 256, 0, stream>>>(u, acc2);
        finalize_kernel<<<1, 1, 0, stream>>>(acc2, out);
    }
}

// Round 15
// 83.670 us; speedup vs baseline: 4.6644x; 1.0911x over previous
//
#include <hip/hip_runtime.h>
#include <hip/hip_bf16.h>
#include <math.h>

#define NROWS 2048
#define BITS  64
#define NCLS  100
#define ALPHA_C  1.0f
#define LAMBDA_C 1.0f
#define ECLAMP   1.0e9f   // setup-clamp: Eb*ep <= 1e18, pair product <= 1e36 (finite)
#define NPMAX    64       // pos-list capacity (np ~ 20.5 +/- 4.5; 64 = +9.7 sigma)
#define EPS      20       // epT LDS row stride (floats): 80B -> 16B-aligned, conflict-free

typedef __bf16 bf16x8 __attribute__((ext_vector_type(8)));
typedef float  floatx4 __attribute__((ext_vector_type(4)));

// ---------------------------------------------------------------------------
// Fast-path ws layout:
//   [0,      2048)   uchar lab8[2048]
//   [8192,  16384)   float rl[2048]     accumulated sum(log2)*ln2 (prep zeroes)
//   [16384, 24576)   int   npg[2048]    true pos count per row
//   [24576, 24832)   float qp[64]       quant partials
//   [32768, 557056)  float Ep[2048][64] pos-exp lists, zero-padded (posk writes)
//   [557056,819200)  ushort ub[2048*64] bf16 copy of u
// Pipeline: prep -> posk (global pos lists, once) -> evalj2 (register-resident
// MFMA + eval, 16 rows x 256 cols per block) -> finalize.
// This is the round-12 configuration (81.2 us) — best of 7 structural
// variants. Round-13 (grid.sync ~100us each) and round-14 (counter-fold
// finalize, +10us atomic tail) both regressed; reverted.
// Harness poisons full ws every timed call (~41 us HBM fill) + ~25 us graph
// node overhead — fixed floor. Our kernels sit on top (~13 us).
// ---------------------------------------------------------------------------

__device__ __forceinline__ float block_reduce_sum(float v, float* wsum) {
    __syncthreads();
    #pragma unroll
    for (int off = 32; off > 0; off >>= 1) v += __shfl_down(v, off);
    int tid = threadIdx.x;
    if ((tid & 63) == 0) wsum[tid >> 6] = v;
    __syncthreads();
    float r = 0.f;
    if (tid == 0) {
        #pragma unroll
        for (int w = 0; w < 4; ++w) r += wsum[w];
    }
    return r;
}

__device__ __forceinline__ float softplus_mt(float T) {
    return fmaxf(-T, 0.f) + __logf(1.f + __expf(-fabsf(T)));
}

// ===========================================================================
// Fast path
// ===========================================================================

// blocks [0,64): u -> bf16 (RNE) + quant partials.
// blocks [64,576): labels via ballot + zero rl.
__global__ __launch_bounds__(256) void prep_kernel(const float* __restrict__ u,
                                                   const float* __restrict__ y,
                                                   unsigned short* __restrict__ ub,
                                                   unsigned char* __restrict__ lab8,
                                                   float* __restrict__ qp,
                                                   float* __restrict__ rl) {
    const int tid = threadIdx.x;
    if (blockIdx.x < 64) {
        __shared__ float wsum[4];
        const int base = blockIdx.x * 2048 + tid * 8;
        float4 v0 = *(const float4*)(u + base);
        float4 v1 = *(const float4*)(u + base + 4);
        float vv[8] = {v0.x, v0.y, v0.z, v0.w, v1.x, v1.y, v1.z, v1.w};
        unsigned short ob[8];
        float q = 0.f;
        #pragma unroll
        for (int m = 0; m < 8; ++m) {
            const float v = vv[m];
            const float sg = (v > 0.f) ? 1.f : ((v < 0.f) ? -1.f : 0.f);
            const float d = v - sg;
            q = fmaf(d, d, q);
            __hip_bfloat16 h = __float2bfloat16(v);   // RNE
            ob[m] = *reinterpret_cast<unsigned short*>(&h);
        }
        *(uint4*)(ub + base) = *(const uint4*)ob;
        float t = block_reduce_sum(q, wsum);
        if (tid == 0) qp[blockIdx.x] = t;
    } else {
        const int bi = blockIdx.x - 64;               // 0..511
        if (tid == 0) ((float4*)rl)[bi] = make_float4(0.f, 0.f, 0.f, 0.f);
        const int row = bi * 4 + (tid >> 6);
        const int lane = tid & 63;
        const float* yr = y + (size_t)row * NCLS;
        float v0 = yr[lane];
        float v1 = (lane < NCLS - 64) ? yr[lane + 64] : 0.f;
        unsigned long long m0 = __ballot(v0 > 0.5f);
        unsigned long long m1 = __ballot(v1 > 0.5f);
        if (lane == 0) {
            int c = m0 ? (__ffsll(m0) - 1) : (m1 ? 64 + __ffsll(m1) - 1 : 0);
            lab8[row] = (unsigned char)c;
        }
    }
}

// Global pos-exp lists, computed ONCE. One wave per row (512 blocks x 4 waves).
// Phase A: ballot-scan the 2048 labels, compact matched j's into an LDS list
// (no dots under divergence). Phase B: one parallel pass — lane l < np
// computes dot(u[i], u[list[l]]) in fp32. Ep rows zero-padded to 64.
__global__ __launch_bounds__(256) void posk_kernel(const float* __restrict__ u,
                                                   const unsigned char* __restrict__ lab8,
                                                   float* __restrict__ Ep,
                                                   int* __restrict__ npg) {
    __shared__ unsigned char labL[NROWS];   // 2 KB
    __shared__ float uloc[4][BITS];         // 1 KB
    __shared__ int   lstJ[4][NPMAX];        // 1 KB
    const int tid = threadIdx.x;
    const int wave = tid >> 6;
    const int lane = tid & 63;
    const int row = blockIdx.x * 4 + wave;

    ((uint2*)labL)[tid] = ((const uint2*)lab8)[tid];
    uloc[wave][lane] = u[(size_t)row * BITS + lane];
    __syncthreads();

    const int ci = labL[row];
    int np = 0;
    #pragma unroll 4
    for (int m = 0; m < NROWS / 64; ++m) {
        const int j = m * 64 + lane;
        const bool match = (labL[j] == ci);
        unsigned long long bal = __ballot(match);
        if (bal) {
            if (match) {
                const unsigned long long below = (lane == 0) ? 0ull : (bal << (64 - lane));
                const int slot = np + __popcll(below);
                if (slot < NPMAX) lstJ[wave][slot] = j;
            }
            np += __popcll(bal);
        }
    }
    const int npc = (np < NPMAX) ? np : NPMAX;

    float val = 0.f;   // zero-pad default
    if (lane < npc) {
        const int j = lstJ[wave][lane];
        const float4* uj4 = (const float4*)(u + (size_t)j * BITS);
        float s0 = 0.f, s1 = 0.f, s2 = 0.f, s3 = 0.f;
        #pragma unroll
        for (int kk = 0; kk < BITS / 4; ++kk) {
            float4 vj = uj4[kk];
            s0 = fmaf(vj.x, uloc[wave][4 * kk + 0], s0);
            s1 = fmaf(vj.y, uloc[wave][4 * kk + 1], s1);
            s2 = fmaf(vj.z, uloc[wave][4 * kk + 2], s2);
            s3 = fmaf(vj.w, uloc[wave][4 * kk + 3], s3);
        }
        val = fminf(__expf(-((s0 + s1) + (s2 + s3))), ECLAMP);
    }
    Ep[(size_t)row * NPMAX + lane] = val;    // coalesced, full row incl. zero pad
    if (lane == 0) npg[row] = np;
}

// Register-resident MFMA + eval. Grid 1024 = 128 i-tiles x 8 j-eighths.
// Block: 16 rows x 256 cols. Per wave: 4 j-tiles, ALL 4 C-regs used (each
// lane evals 16 G values across its quad's 4 rows). Pos lists enter via
// transposed LDS tile epT[64][EPS]: one conflict-free b128 per pos-index
// feeds a quad's 4 rows. Pair-product log2 (term = ln2*log2(1+Eb*ep); setup
// clamp 1e9 keeps products finite, caps terms at 41.4 — ~2e-4 of pairs,
// loss error ~6e-4 << 0.104 threshold). Zero-pad slots contribute exactly 0.
__global__ __launch_bounds__(256, 4) void evalj2_kernel(const unsigned short* __restrict__ ub,
                                                        const unsigned char* __restrict__ lab8,
                                                        const float* __restrict__ Ep,
                                                        const int* __restrict__ npg,
                                                        float* __restrict__ rl) {
    __shared__ unsigned char labL[NROWS];     // 2 KB
    alignas(16) __shared__ float epT[NPMAX][EPS];         // 5 KB transposed pos lists
    __shared__ int np16[16];
    __shared__ float wsum[16][4];

    const int tid  = threadIdx.x;
    const int wave = tid >> 6;
    const int lane = tid & 63;
    const int rsel = lane & 15;
    const int quad = lane >> 4;
    const int koff = quad * 8;
    const int i0    = (blockIdx.x >> 3) * 16;
    const int jbase = (blockIdx.x & 7) * 256;

    ((uint2*)labL)[tid] = ((const uint2*)lab8)[tid];
    // stage epT[k][r] = Ep[i0+r][k]  (coalesced reads, padded-stride writes)
    #pragma unroll
    for (int it = 0; it < 4; ++it) {
        const int idx = tid + it * 256;          // 0..1023
        const int r = idx >> 6, k = idx & 63;
        epT[k][r] = Ep[(size_t)(i0 + r) * NPMAX + k];
    }
    if (tid < 16) np16[tid] = npg[i0 + tid];

    // ---- MFMA: 4 tiles/wave, keep all 4 C-regs; build Eb immediately ----
    uint4 a0r = *(const uint4*)(ub + (size_t)(i0 + rsel) * BITS + koff);
    uint4 a1r = *(const uint4*)(ub + (size_t)(i0 + rsel) * BITS + 32 + koff);
    bf16x8 A0 = __builtin_bit_cast(bf16x8, a0r);
    bf16x8 A1 = __builtin_bit_cast(bf16x8, a1r);

    float Eb[4][4];
    #pragma unroll
    for (int t = 0; t < 4; ++t) {
        const int jr = jbase + (wave * 4 + t) * 16 + rsel;
        uint4 b0r = *(const uint4*)(ub + (size_t)jr * BITS + koff);
        uint4 b1r = *(const uint4*)(ub + (size_t)jr * BITS + 32 + koff);
        bf16x8 B0 = __builtin_bit_cast(bf16x8, b0r);
        bf16x8 B1 = __builtin_bit_cast(bf16x8, b1r);
        floatx4 c = {0.f, 0.f, 0.f, 0.f};
        c = __builtin_amdgcn_mfma_f32_16x16x32_bf16(A0, B0, c, 0, 0, 0);
        c = __builtin_amdgcn_mfma_f32_16x16x32_bf16(A1, B1, c, 0, 0, 0);
        #pragma unroll
        for (int r = 0; r < 4; ++r) {
            // G value row = i0 + 4*quad + r, col = jr
            const int rowLab = labL[i0 + 4 * quad + r];
            const int colLab = labL[jr];
            Eb[t][r] = (colLab == rowLab) ? 0.f
                                          : fminf(__expf(c[r] + ALPHA_C), ECLAMP);
        }
    }
    __syncthreads();   // epT + np16 visible

    int npmx = 0;
    #pragma unroll
    for (int r = 0; r < 16; ++r) {
        int n = np16[r]; n = (n > NPMAX) ? NPMAX : n;
        npmx = (n > npmx) ? n : npmx;
    }
    const int npr = (npmx + 1) & ~1;   // even bound for pairing

    float s[4] = {0.f, 0.f, 0.f, 0.f};
    for (int k = 0; k < npr; k += 2) {
        const float4 e0 = *(const float4*)(&epT[k][4 * quad]);       // b128, no conflict
        const float4 e1 = *(const float4*)(&epT[k + 1][4 * quad]);
        const float e0v[4] = {e0.x, e0.y, e0.z, e0.w};
        const float e1v[4] = {e1.x, e1.y, e1.z, e1.w};
        #pragma unroll
        for (int t = 0; t < 4; ++t) {
            #pragma unroll
            for (int r = 0; r < 4; ++r) {
                const float q0 = Eb[t][r];
                const float f = fmaf(q0, e0v[r], 1.f);
                const float g = fmaf(q0, e1v[r], 1.f);
                s[r] += __log2f(f * g);
            }
        }
    }

    // ---- reduce: 16-lane quad groups -> per-row, then across 4 waves ----
    #pragma unroll
    for (int r = 0; r < 4; ++r) {
        #pragma unroll
        for (int off = 1; off < 16; off <<= 1) s[r] += __shfl_xor(s[r], off);
    }
    if (rsel == 0) {
        #pragma unroll
        for (int r = 0; r < 4; ++r) wsum[4 * quad + r][wave] = s[r];
    }
    __syncthreads();
    if (tid < 16) {
        const float ln2 = 0.6931471805599453f;
        const float tot = ((wsum[tid][0] + wsum[tid][1]) +
                           (wsum[tid][2] + wsum[tid][3])) * ln2;
        atomicAdd(&rl[i0 + tid], tot);   // 8 adds per row total (one per j-eighth)
    }
}

__global__ __launch_bounds__(256) void finalize3_kernel(const float* __restrict__ rl,
                                                        const int* __restrict__ npg,
                                                        const float* __restrict__ qp,
                                                        float* __restrict__ out) {
    __shared__ float wsum[4];
    const int tid = threadIdx.x;
    float t = 0.f, v = 0.f;
    for (int row = tid; row < NROWS; row += 256) {
        const int np = npg[row];
        const int nneg = NROWS - np;
        const int valid = (np > 0 && nneg > 0) ? 1 : 0;
        t += valid ? (rl[row] / fmaxf((float)np * (float)nneg, 1.f)) : 0.f;
        v += (float)valid;
    }
    float q = (tid < 64) ? qp[tid] : 0.f;
    float tt = block_reduce_sum(t, wsum);
    float vv = block_reduce_sum(v, wsum);
    float qq = block_reduce_sum(q, wsum);
    if (tid == 0) {
        const float loss1 = (vv > 0.f) ? (tt / fmaxf(vv, 1.f)) : 0.f;
        const float loss2 = LAMBDA_C * (qq / (float)(NROWS * BITS));
        out[0] = loss1 + loss2;
    }
}

// ===========================================================================
// Fallback path (small ws) — unchanged (passed round 1)
// ===========================================================================

__global__ __launch_bounds__(256) void labels_only_kernel(const float* __restrict__ y,
                                                          int* __restrict__ labels) {
    const int tid = threadIdx.x;
    const int row = blockIdx.x * 4 + (tid >> 6);
    const int lane = tid & 63;
    const float* yr = y + (size_t)row * NCLS;
    float v0 = yr[lane];
    float v1 = (lane < NCLS - 64) ? yr[lane + 64] : 0.f;
    unsigned long long m0 = __ballot(v0 > 0.5f);
    unsigned long long m1 = __ballot(v1 > 0.5f);
    if (lane == 0) {
        int c = m0 ? (__ffsll(m0) - 1) : (m1 ? 64 + __ffsll(m1) - 1 : 0);
        labels[row] = c;
    }
}

__global__ __launch_bounds__(256) void row_loss_kernel(const float* __restrict__ u,
                                                       const int* __restrict__ labels,
                                                       float* __restrict__ acc) {
    __shared__ float a[NROWS];
    __shared__ float apv[NROWS];
    __shared__ int lab[NROWS];
    __shared__ float ui[BITS];
    __shared__ int npos_s;
    __shared__ float wsum[4];

    const int i = blockIdx.x;
    const int tid = threadIdx.x;

    if (tid < BITS) ui[tid] = u[(size_t)i * BITS + tid];
    if (tid == 0) npos_s = 0;
    __syncthreads();

    #pragma unroll
    for (int m = 0; m < NROWS / 256; ++m) {
        const int j = tid + m * 256;
        const float4* uj = (const float4*)(u + (size_t)j * BITS);
        float s0 = 0.f, s1 = 0.f, s2 = 0.f, s3 = 0.f;
        #pragma unroll
        for (int q = 0; q < BITS / 4; ++q) {
            float4 v = uj[q];
            s0 = fmaf(v.x, ui[4 * q + 0], s0);
            s1 = fmaf(v.y, ui[4 * q + 1], s1);
            s2 = fmaf(v.z, ui[4 * q + 2], s2);
            s3 = fmaf(v.w, ui[4 * q + 3], s3);
        }
        a[j] = (s0 + s1) + (s2 + s3);
        lab[j] = labels[j];
    }
    __syncthreads();

    const int c = lab[i];
    #pragma unroll
    for (int m = 0; m < NROWS / 256; ++m) {
        const int j = tid + m * 256;
        if (lab[j] == c) { int k = atomicAdd(&npos_s, 1); apv[k] = a[j]; }
    }
    __syncthreads();
    const int npos = npos_s;
    const int nneg = NROWS - npos;

    float bb[NROWS / 256];
    #pragma unroll
    for (int m = 0; m < NROWS / 256; ++m) {
        const int j = tid + m * 256;
        bb[m] = (lab[j] != c) ? (a[j] + ALPHA_C) : -3.0e38f;
    }

    float lsum = 0.f;
    for (int k = 0; k < npos; ++k) {
        const float apk = apv[k];
        #pragma unroll
        for (int m = 0; m < NROWS / 256; ++m) lsum += softplus_mt(apk - bb[m]);
    }

    float tot = block_reduce_sum(lsum, wsum);
    if (tid == 0) {
        const int valid = (npos > 0 && nneg > 0) ? 1 : 0;
        const float npairs = fmaxf((float)npos * (float)nneg, 1.f);
        const float rlv = valid ? (tot / npairs) : 0.f;
        atomicAdd(&acc[0], rlv);
        atomicAdd(&acc[1], (float)valid);
    }
}

__global__ __launch_bounds__(256) void quant_kernel(const float* __restrict__ u,
                                                    float* __restrict__ acc) {
    __shared__ float wsum[4];
    const int stride = gridDim.x * 256;
    float s = 0.f;
    for (int t = blockIdx.x * 256 + threadIdx.x; t < NROWS * BITS; t += stride) {
        float v = u[t];
        float sg = (v > 0.f) ? 1.f : ((v < 0.f) ? -1.f : 0.f);
        float d = v - sg;
        s = fmaf(d, d, s);
    }
    float tot = block_reduce_sum(s, wsum);
    if (threadIdx.x == 0) atomicAdd(&acc[2], tot);
}

__global__ void finalize_kernel(const float* __restrict__ acc,
                                float* __restrict__ out) {
    const float tot = acc[0], cnt = acc[1], q = acc[2];
    const float loss1 = (cnt > 0.f) ? (tot / fmaxf(cnt, 1.f)) : 0.f;
    const float loss2 = LAMBDA_C * (q / (float)(NROWS * BITS));
    out[0] = loss1 + loss2;
}

// ===========================================================================

extern "C" void kernel_launch(void* const* d_in, const int* in_sizes, int n_in,
                              void* d_out, int out_size, void* d_ws, size_t ws_size,
                              hipStream_t stream) {
    const float* u = (const float*)d_in[0];   // [2048, 64]
    const float* y = (const float*)d_in[1];   // [2048, 100]
    float* out = (float*)d_out;

    unsigned char* lab8 = (unsigned char*)d_ws;
    float* rl  = (float*)((char*)d_ws + 8192);
    int*   npg = (int*)((char*)d_ws + 16384);
    float* qp  = (float*)((char*)d_ws + 24576);
    float* Ep  = (float*)((char*)d_ws + 32768);
    unsigned short* ub = (unsigned short*)((char*)d_ws + 557056);
    const size_t NEED = 557056 + (size_t)NROWS * BITS * sizeof(unsigned short);

    if (ws_size >= NEED) {
        prep_kernel<<<576, 256, 0, stream>>>(u, y, ub, lab8, qp, rl);
        posk_kernel<<<512, 256, 0, stream>>>(u, lab8, Ep, npg);
        evalj2_kernel<<<1024, 256, 0, stream>>>(ub, lab8, Ep, npg, rl);
        finalize3_kernel<<<1, 256, 0, stream>>>(rl, npg, qp, out);
    } else {
        float* acc2 = (float*)d_ws;
        int*   lab2 = (int*)((char*)d_ws + 256);
        hipMemsetAsync(d_ws, 0, 256, stream);
        labels_only_kernel<<<512, 256, 0, stream>>>(y, lab2);
        row_loss_kernel<<<NROWS, 256, 0, stream>>>(u, lab2, acc2);
        quant_kernel<<<64, 256, 0, stream>>>(u, acc2);
        finalize_kernel<<<1, 1, 0, stream>>>(acc2, out);
    }
}